// Round 1
// baseline (1342.416 us; speedup 1.0000x reference)
//
#include <hip/hip_runtime.h>
#include <stdint.h>
#include <math.h>

#define NB      8
#define NPTS    16384
#define NPOINT  512
#define NCH     128
#define KNBR    32
#define R2      0.04f

// -------- kernel 1: FPS (blocks 0..7) fused with feature transpose ----------
// FPS: one block per batch, 1024 threads, 16 points/thread in registers.
// Bit-exact replication of reference fp32 math (no FMA contraction).
__global__ __launch_bounds__(1024, 4)
void fps_transpose_kernel(const float* __restrict__ xyz,
                          const float* __restrict__ feat,
                          float* __restrict__ out,     // new_xyz at [0,12288)
                          int* __restrict__ cent,      // ws: 8*512 ints
                          float* __restrict__ ft,      // ws: (B,N,128) fp32
                          int use_ft)
{
    const int blk = blockIdx.x;
    const int tid = threadIdx.x;

    if (blk < NB) {
        const int b = blk;
        const float* xb = xyz + (size_t)b * NPTS * 3;
        float px[16], py[16], pz[16], dist[16];
#pragma unroll
        for (int k = 0; k < 16; ++k) {
            int p = k * 1024 + tid;
            px[k] = xb[p * 3 + 0];
            py[k] = xb[p * 3 + 1];
            pz[k] = xb[p * 3 + 2];
            dist[k] = 1e10f;
        }
        __shared__ float s_v[16];
        __shared__ int   s_p[16];
        const int lane = tid & 63;
        const int wid  = tid >> 6;

        int cur = 0;
        if (tid == 0) {
            cent[b * NPOINT + 0] = 0;
            out[((size_t)b * NPOINT + 0) * 3 + 0] = xb[0];
            out[((size_t)b * NPOINT + 0) * 3 + 1] = xb[1];
            out[((size_t)b * NPOINT + 0) * 3 + 2] = xb[2];
        }

        for (int i = 1; i < NPOINT; ++i) {
            float cx = xb[cur * 3 + 0];
            float cy = xb[cur * 3 + 1];
            float cz = xb[cur * 3 + 2];
            float bv = -1.0f; int bk = 0;
#pragma unroll
            for (int k = 0; k < 16; ++k) {
                float dx = __fsub_rn(px[k], cx);
                float dy = __fsub_rn(py[k], cy);
                float dz = __fsub_rn(pz[k], cz);
                float d  = __fadd_rn(__fadd_rn(__fmul_rn(dx, dx),
                                               __fmul_rn(dy, dy)),
                                     __fmul_rn(dz, dz));
                float nd = fminf(dist[k], d);   // np.minimum
                dist[k] = nd;
                if (nd > bv) { bv = nd; bk = k; }   // strict >: earliest k wins
            }
            int bp = bk * 1024 + tid;  // global point index of local best
            // wave argmax (value desc, index asc tiebreak)
#pragma unroll
            for (int off = 1; off < 64; off <<= 1) {
                float ov = __shfl_xor(bv, off);
                int   op = __shfl_xor(bp, off);
                if (ov > bv || (ov == bv && op < bp)) { bv = ov; bp = op; }
            }
            if (lane == 0) { s_v[wid] = bv; s_p[wid] = bp; }
            __syncthreads();
            {
                int g = lane & 15;
                float v2 = s_v[g];
                int   p2 = s_p[g];
#pragma unroll
                for (int off = 1; off < 16; off <<= 1) {
                    float ov = __shfl_xor(v2, off);
                    int   op = __shfl_xor(p2, off);
                    if (ov > v2 || (ov == v2 && op < p2)) { v2 = ov; p2 = op; }
                }
                cur = __builtin_amdgcn_readfirstlane(p2);
            }
            if (tid == 0) {
                cent[b * NPOINT + i] = cur;
                out[((size_t)b * NPOINT + i) * 3 + 0] = xb[cur * 3 + 0];
                out[((size_t)b * NPOINT + i) * 3 + 1] = xb[cur * 3 + 1];
                out[((size_t)b * NPOINT + i) * 3 + 2] = xb[cur * 3 + 2];
            }
            __syncthreads();   // protect s_v/s_p before next iteration
        }
    } else {
        if (!use_ft) return;
        // transpose feat (B,128,N) -> ft (B,N,128), 32x32 tiles, 1024 thr
        int t  = blk - NB;
        int b  = t >> 11;          // /2048 tiles per batch
        int r  = t & 2047;
        int ct = r >> 9;           // channel tile (4)
        int nt = r & 511;          // point tile (512)
        __shared__ float tile[32][33];
        int tx = tid & 31, ty = tid >> 5;
        int c = ct * 32 + ty, n = nt * 32 + tx;
        tile[ty][tx] = feat[((size_t)b * NCH + c) * NPTS + n];
        __syncthreads();
        int n2 = nt * 32 + ty, c2 = ct * 32 + tx;
        ft[((size_t)b * NPTS + n2) * NCH + c2] = tile[tx][ty];
    }
}

// -------- kernel 2: ball query + grouped max pool ---------------------------
// One wave per centroid (4096 waves). Collect first 32 in-ball indices
// (ascending) via ballot+prefix, then max over feature rows.
__global__ __launch_bounds__(256, 4)
void query_pool_kernel(const float* __restrict__ xyz,
                       const float* __restrict__ feat,
                       const float* __restrict__ ft,
                       const int* __restrict__ cent,
                       float* __restrict__ out_sub,   // (B,128,512)
                       int use_ft)
{
    const int tid  = threadIdx.x;
    const int widx = tid >> 6;
    const int lane = tid & 63;
    const int w = blockIdx.x * 4 + widx;   // 0..4095
    const int b = w >> 9;
    const int s = w & 511;

    const float* xb = xyz + (size_t)b * NPTS * 3;
    const int ci = cent[b * NPOINT + s];
    const float sx = xb[ci * 3 + 0];
    const float sy = xb[ci * 3 + 1];
    const float sz = xb[ci * 3 + 2];
    const float snorm = __fadd_rn(__fadd_rn(__fmul_rn(sx, sx),
                                            __fmul_rn(sy, sy)),
                                  __fmul_rn(sz, sz));

    __shared__ int lidx[4][KNBR];
    int found = 0;
    for (int base = 0; base < NPTS && found < KNBR; base += 64) {
        int j = base + lane;
        float dx = xb[j * 3 + 0];
        float dy = xb[j * 3 + 1];
        float dz = xb[j * 3 + 2];
        float dn = __fadd_rn(__fadd_rn(__fmul_rn(dx, dx),
                                       __fmul_rn(dy, dy)),
                             __fmul_rn(dz, dz));
        float dot = __fadd_rn(__fadd_rn(__fmul_rn(sx, dx),
                                        __fmul_rn(sy, dy)),
                              __fmul_rn(sz, dz));
        // reference order: d = -2*dot; d += snorm; d += dnorm
        float d = __fadd_rn(__fadd_rn(__fmul_rn(-2.0f, dot), snorm), dn);
        bool inball = !(d > R2);
        unsigned long long mask = __ballot(inball);
        int before = (int)__popcll(mask & ((1ULL << lane) - 1ULL));
        int slot = found + before;
        if (inball && slot < KNBR) lidx[widx][slot] = j;
        found += (int)__popcll(mask);
    }
    int cnt = found < KNBR ? found : KNBR;   // cnt >= 1 always (self in ball)
    __syncthreads();   // make lidx visible (all 256 threads reach this once)

    float a0 = -INFINITY, a1 = -INFINITY;
    if (use_ft) {
        for (int m = 0; m < cnt; ++m) {
            int i = lidx[widx][m];
            const float* row = ft + ((size_t)b * NPTS + i) * NCH;
            a0 = fmaxf(a0, row[lane]);
            a1 = fmaxf(a1, row[lane + 64]);
        }
    } else {
        for (int m = 0; m < cnt; ++m) {
            int i = lidx[widx][m];
            a0 = fmaxf(a0, feat[((size_t)b * NCH + lane) * NPTS + i]);
            a1 = fmaxf(a1, feat[((size_t)b * NCH + lane + 64) * NPTS + i]);
        }
    }
    out_sub[((size_t)b * NCH + lane) * NPOINT + s] = a0;
    out_sub[((size_t)b * NCH + lane + 64) * NPOINT + s] = a1;
}

extern "C" void kernel_launch(void* const* d_in, const int* in_sizes, int n_in,
                              void* d_out, int out_size, void* d_ws, size_t ws_size,
                              hipStream_t stream)
{
    const float* xyz  = (const float*)d_in[0];   // (8,16384,3)
    const float* feat = (const float*)d_in[1];   // (8,128,16384)
    float* out = (float*)d_out;                  // [new_xyz | sub_features]

    int*   cent = (int*)d_ws;                              // 16 KB
    float* ft   = (float*)((char*)d_ws + 16384);           // 67 MB transposed
    const size_t need_ft = 16384ull + (size_t)NB * NPTS * NCH * 4ull;
    int use_ft = (ws_size >= need_ft) ? 1 : 0;

    int nblocks1 = use_ft ? (NB + NB * (NCH / 32) * (NPTS / 32)) : NB;
    hipLaunchKernelGGL(fps_transpose_kernel, dim3(nblocks1), dim3(1024), 0, stream,
                       xyz, feat, out, cent, ft, use_ft);

    hipLaunchKernelGGL(query_pool_kernel, dim3((NB * NPOINT) / 4), dim3(256), 0, stream,
                       xyz, feat, ft, cent, out + (size_t)NB * NPOINT * 3, use_ft);
}

// Round 2
// 1172.778 us; speedup vs baseline: 1.1446x; 1.1446x over previous
//
#include <hip/hip_runtime.h>
#include <stdint.h>
#include <math.h>

#define NB      8
#define NPTS    16384
#define NPOINT  512
#define NCH     128
#define KNBR    32
#define R2      0.04f

// argmax step over (value desc, index asc) using DPP permute (VALU latency)
#define DPP_ARG_STEP(v, p, CTRL) do {                                          \
    float _ov = __builtin_bit_cast(float, __builtin_amdgcn_update_dpp(         \
        __builtin_bit_cast(int, (v)), __builtin_bit_cast(int, (v)),            \
        (CTRL), 0xF, 0xF, false));                                             \
    int _op = __builtin_amdgcn_update_dpp((p), (p), (CTRL), 0xF, 0xF, false);  \
    bool _t = (_ov > (v)) || ((_ov == (v)) && (_op < (p)));                    \
    (v) = _t ? _ov : (v);                                                      \
    (p) = _t ? _op : (p);                                                      \
} while (0)

#define SHFL_ARG_STEP(v, p, XORAMT) do {                                       \
    float _ov = __shfl_xor((v), (XORAMT), 64);                                 \
    int   _op = __shfl_xor((p), (XORAMT), 64);                                 \
    bool _t = (_ov > (v)) || ((_ov == (v)) && (_op < (p)));                    \
    (v) = _t ? _ov : (v);                                                      \
    (p) = _t ? _op : (p);                                                      \
} while (0)

// -------- kernel 1: FPS (blocks 0..7) fused with feature transpose ----------
// Pin exactly 4 waves/EU (1 block of 16 waves per CU): removes any occupancy
// incentive for the register allocator to spill the 64-reg point arrays.
__global__
__attribute__((amdgpu_flat_work_group_size(1024, 1024)))
__attribute__((amdgpu_waves_per_eu(4, 4)))
void fps_transpose_kernel(const float* __restrict__ xyz,
                          const float* __restrict__ feat,
                          float* __restrict__ out,     // new_xyz at [0,12288)
                          int* __restrict__ cent,      // ws: 8*512 ints
                          float* __restrict__ ft,      // ws: (B,N,128) fp32
                          int use_ft)
{
    const int blk = blockIdx.x;
    const int tid = threadIdx.x;

    if (blk < NB) {
        const int b = blk;
        const float* xb = xyz + (size_t)b * NPTS * 3;
        float px[16], py[16], pz[16], dist[16];
#pragma unroll
        for (int k = 0; k < 16; ++k) {
            int p = k * 1024 + tid;
            px[k] = xb[p * 3 + 0];
            py[k] = xb[p * 3 + 1];
            pz[k] = xb[p * 3 + 2];
            dist[k] = 1e10f;
        }
        __shared__ float s_v[16];
        __shared__ int   s_p[16];
        __shared__ float s_cx, s_cy, s_cz;
        const int lane = tid & 63;
        const int wid  = tid >> 6;

        if (tid == 0) {
            cent[b * NPOINT + 0] = 0;
            out[((size_t)b * NPOINT + 0) * 3 + 0] = xb[0];
            out[((size_t)b * NPOINT + 0) * 3 + 1] = xb[1];
            out[((size_t)b * NPOINT + 0) * 3 + 2] = xb[2];
            s_cx = xb[0]; s_cy = xb[1]; s_cz = xb[2];
        }
        __syncthreads();

        for (int i = 1; i < NPOINT; ++i) {
            const float cx = s_cx, cy = s_cy, cz = s_cz;
            float bv = -1.0f; int bk = 0;
#pragma unroll
            for (int k = 0; k < 16; ++k) {
                float dx = __fsub_rn(px[k], cx);
                float dy = __fsub_rn(py[k], cy);
                float dz = __fsub_rn(pz[k], cz);
                float d  = __fadd_rn(__fadd_rn(__fmul_rn(dx, dx),
                                               __fmul_rn(dy, dy)),
                                     __fmul_rn(dz, dz));
                float nd = fminf(dist[k], d);   // np.minimum, exact
                dist[k] = nd;
                if (nd > bv) { bv = nd; bk = k; }  // strict >: earliest k wins
            }
            float rv = bv;
            int   rp = bk * 1024 + tid;  // global point index of local best
            // wave argmax: 4 DPP steps (VALU latency) + 2 shuffles
            DPP_ARG_STEP(rv, rp, 0xB1);   // quad_perm(1,0,3,2)  xor 1
            DPP_ARG_STEP(rv, rp, 0x4E);   // quad_perm(2,3,0,1)  xor 2
            DPP_ARG_STEP(rv, rp, 0x141);  // row_half_mirror     pairs 4-grps
            DPP_ARG_STEP(rv, rp, 0x140);  // row_mirror          pairs 8-grps
            SHFL_ARG_STEP(rv, rp, 16);
            SHFL_ARG_STEP(rv, rp, 32);
            if (lane == 0) { s_v[wid] = rv; s_p[wid] = rp; }
            __syncthreads();   // A: partials visible
            // all waves redundantly reduce the 16 partials (4 DPP steps)
            float fv = s_v[lane & 15];
            int   fp = s_p[lane & 15];
            DPP_ARG_STEP(fv, fp, 0xB1);
            DPP_ARG_STEP(fv, fp, 0x4E);
            DPP_ARG_STEP(fv, fp, 0x141);
            DPP_ARG_STEP(fv, fp, 0x140);
            const int cur = __builtin_amdgcn_readfirstlane(fp);
            if (tid == (cur & 1023)) {
                const int kk = cur >> 10;   // wave-uniform (SGPR) -> s_cbranch
                float ox = 0.f, oy = 0.f, oz = 0.f;
#define CASE_K(K) case K: ox = px[K]; oy = py[K]; oz = pz[K]; break;
                switch (kk) {
                    CASE_K(0)  CASE_K(1)  CASE_K(2)  CASE_K(3)
                    CASE_K(4)  CASE_K(5)  CASE_K(6)  CASE_K(7)
                    CASE_K(8)  CASE_K(9)  CASE_K(10) CASE_K(11)
                    CASE_K(12) CASE_K(13) CASE_K(14) CASE_K(15)
                }
#undef CASE_K
                s_cx = ox; s_cy = oy; s_cz = oz;
                cent[b * NPOINT + i] = cur;
                size_t o = ((size_t)b * NPOINT + i) * 3;
                out[o + 0] = ox; out[o + 1] = oy; out[o + 2] = oz;
            }
            __syncthreads();   // B: new centroid coords visible
        }
    } else {
        if (!use_ft) return;
        // transpose feat (B,128,N) -> ft (B,N,128), 32x32 tiles, 1024 thr
        int t  = blk - NB;
        int b  = t >> 11;          // /2048 tiles per batch
        int r  = t & 2047;
        int ct = r >> 9;           // channel tile (4)
        int nt = r & 511;          // point tile (512)
        __shared__ float tile[32][33];
        int tx = tid & 31, ty = tid >> 5;
        int c = ct * 32 + ty, n = nt * 32 + tx;
        tile[ty][tx] = feat[((size_t)b * NCH + c) * NPTS + n];
        __syncthreads();
        int n2 = nt * 32 + ty, c2 = ct * 32 + tx;
        ft[((size_t)b * NPTS + n2) * NCH + c2] = tile[tx][ty];
    }
}

// -------- kernel 2: ball query + grouped max pool ---------------------------
__global__ __launch_bounds__(256, 4)
void query_pool_kernel(const float* __restrict__ xyz,
                       const float* __restrict__ feat,
                       const float* __restrict__ ft,
                       const int* __restrict__ cent,
                       float* __restrict__ out_sub,   // (B,128,512)
                       int use_ft)
{
    const int tid  = threadIdx.x;
    const int widx = tid >> 6;
    const int lane = tid & 63;
    const int w = blockIdx.x * 4 + widx;   // 0..4095
    const int b = w >> 9;
    const int s = w & 511;

    const float* xb = xyz + (size_t)b * NPTS * 3;
    const int ci = cent[b * NPOINT + s];
    const float sx = xb[ci * 3 + 0];
    const float sy = xb[ci * 3 + 1];
    const float sz = xb[ci * 3 + 2];
    const float snorm = __fadd_rn(__fadd_rn(__fmul_rn(sx, sx),
                                            __fmul_rn(sy, sy)),
                                  __fmul_rn(sz, sz));

    __shared__ int lidx[4][KNBR];
    int found = 0;
    for (int base = 0; base < NPTS && found < KNBR; base += 64) {
        int j = base + lane;
        float dx = xb[j * 3 + 0];
        float dy = xb[j * 3 + 1];
        float dz = xb[j * 3 + 2];
        float dn = __fadd_rn(__fadd_rn(__fmul_rn(dx, dx),
                                       __fmul_rn(dy, dy)),
                             __fmul_rn(dz, dz));
        float dot = __fadd_rn(__fadd_rn(__fmul_rn(sx, dx),
                                        __fmul_rn(sy, dy)),
                              __fmul_rn(sz, dz));
        // reference order: d = -2*dot; d += snorm; d += dnorm
        float d = __fadd_rn(__fadd_rn(__fmul_rn(-2.0f, dot), snorm), dn);
        bool inball = !(d > R2);
        unsigned long long mask = __ballot(inball);
        int before = (int)__popcll(mask & ((1ULL << lane) - 1ULL));
        int slot = found + before;
        if (inball && slot < KNBR) lidx[widx][slot] = j;
        found += (int)__popcll(mask);
    }
    int cnt = found < KNBR ? found : KNBR;   // cnt >= 1 (self in ball)
    __syncthreads();

    float a0 = -INFINITY, a1 = -INFINITY;
    if (use_ft) {
        for (int m = 0; m < cnt; ++m) {
            int i = lidx[widx][m];
            const float* row = ft + ((size_t)b * NPTS + i) * NCH;
            a0 = fmaxf(a0, row[lane]);
            a1 = fmaxf(a1, row[lane + 64]);
        }
    } else {
        for (int m = 0; m < cnt; ++m) {
            int i = lidx[widx][m];
            a0 = fmaxf(a0, feat[((size_t)b * NCH + lane) * NPTS + i]);
            a1 = fmaxf(a1, feat[((size_t)b * NCH + lane + 64) * NPTS + i]);
        }
    }
    out_sub[((size_t)b * NCH + lane) * NPOINT + s] = a0;
    out_sub[((size_t)b * NCH + lane + 64) * NPOINT + s] = a1;
}

extern "C" void kernel_launch(void* const* d_in, const int* in_sizes, int n_in,
                              void* d_out, int out_size, void* d_ws, size_t ws_size,
                              hipStream_t stream)
{
    const float* xyz  = (const float*)d_in[0];   // (8,16384,3)
    const float* feat = (const float*)d_in[1];   // (8,128,16384)
    float* out = (float*)d_out;                  // [new_xyz | sub_features]

    int*   cent = (int*)d_ws;                              // 16 KB
    float* ft   = (float*)((char*)d_ws + 16384);           // 67 MB transposed
    const size_t need_ft = 16384ull + (size_t)NB * NPTS * NCH * 4ull;
    int use_ft = (ws_size >= need_ft) ? 1 : 0;

    int nblocks1 = use_ft ? (NB + NB * (NCH / 32) * (NPTS / 32)) : NB;
    hipLaunchKernelGGL(fps_transpose_kernel, dim3(nblocks1), dim3(1024), 0, stream,
                       xyz, feat, out, cent, ft, use_ft);

    hipLaunchKernelGGL(query_pool_kernel, dim3((NB * NPOINT) / 4), dim3(256), 0, stream,
                       xyz, feat, ft, cent, out + (size_t)NB * NPOINT * 3, use_ft);
}